// Round 5
// baseline (1875.138 us; speedup 1.0000x reference)
//
#include <hip/hip_runtime.h>

#define NN 50000
#define NE 800000
#define HD 128
#define DEPTH 5
#define NG 64
#define LNEPS 1e-5f

typedef __attribute__((ext_vector_type(8))) short bf8;   // 8 x bf16
typedef __attribute__((ext_vector_type(4))) float f4;

// hardware RNE f32->bf16 pair converter: [lo=cvt(a), hi=cvt(b)]
static __device__ __forceinline__ unsigned int cvt2bf(float a, float b) {
    unsigned int r;
    asm("v_cvt_pk_bf16_f32 %0, %1, %2" : "=v"(r) : "v"(a), "v"(b));
    return r;
}
static __device__ __forceinline__ unsigned short bf1(float x) {
    return (unsigned short)cvt2bf(x, x);
}

// ---------------------------------------------------------------------------
// Pack weights (K x 128 f32 row-major) into bf16 MFMA B-fragment layout:
// packed[s*4096 + f*512 + lane*8 + e] = W[krow][f*16 + (lane&15)],
// krow = s*32 + (lane>>4)*8 + e, except for the K=128 second-layer mats
// (which&1): krow = pinv(k) = (k&7)*16 + (k>>3) — matches the p-space t1
// layout (p(n) = (n&15)*8 + (n>>4)) used for the GEMM2 A-operand.
// ---------------------------------------------------------------------------
__global__ void pack_weights(const float* __restrict__ msg_w1, const float* __restrict__ msg_w2,
                             const float* __restrict__ upd_w1, const float* __restrict__ upd_w2,
                             unsigned short* __restrict__ packed) {
    const int which = blockIdx.y & 3, layer = blockIdx.y >> 2;
    const int t = blockIdx.x * 256 + threadIdx.x;
    const float* src; int K; unsigned short* dst;
    unsigned short* lbase = packed + layer * 98304;
    if (which == 0)      { src = msg_w1 + layer*257*HD; K = 256; dst = lbase; }
    else if (which == 1) { src = msg_w2 + layer*HD*HD;  K = 128; dst = lbase + 32768; }
    else if (which == 2) { src = upd_w1 + layer*256*HD; K = 256; dst = lbase + 49152; }
    else                 { src = upd_w2 + layer*HD*HD;  K = 128; dst = lbase + 81920; }
    if (t >= K * HD) return;
    const int e = t & 7, l = (t >> 3) & 63, f = (t >> 9) & 7, s = t >> 12;
    const int kk = s*32 + ((l >> 4) << 3) + e;
    const int k = (which & 1) ? ((kk & 7)*16 + (kk >> 3)) : kk;   // pinv for layer-2 mats
    const int n = f*16 + (l & 15);
    dst[t] = bf1(src[k*HD + n]);
}

__global__ void embed_kernel(const float* __restrict__ x, const float* __restrict__ emb_w,
                             const float* __restrict__ emb_b,
                             float* __restrict__ h, unsigned short* __restrict__ hb) {
    const int i = blockIdx.x * 256 + threadIdx.x;      // N*H exact
    const int n = i >> 7, j = i & 127;
    const float v = x[n] * emb_w[j] + emb_b[j];
    h[i] = v; hb[i] = bf1(v);
}

// --------------------- counting sort of edges by dst -----------------------
__global__ void hist_kernel(const int* __restrict__ ei, int* __restrict__ cnt) {
    const int e = blockIdx.x * 256 + threadIdx.x;      // NE exact
    atomicAdd(&cnt[ei[NE + e]], 1);
}

__global__ __launch_bounds__(1024) void scan_kernel(const int* __restrict__ cnt,
                                                    int* __restrict__ cur) {
    __shared__ int part[1024];
    const int t = threadIdx.x;
    const int per = 49;                                 // 1024*49 >= NN
    const int base = t * per;
    int s = 0;
    for (int i = 0; i < per; ++i) { const int idx = base + i; if (idx < NN) s += cnt[idx]; }
    part[t] = s; __syncthreads();
    for (int st = 1; st < 1024; st <<= 1) {
        const int v = (t >= st) ? part[t - st] : 0;
        __syncthreads();
        part[t] += v;
        __syncthreads();
    }
    int run = (t == 0) ? 0 : part[t - 1];
    for (int i = 0; i < per; ++i) {
        const int idx = base + i;
        if (idx < NN) { cur[idx] = run; run += cnt[idx]; }
    }
}

__global__ void scatter_kernel(const int* __restrict__ ei, int* __restrict__ cur,
                               int* __restrict__ sidx, int* __restrict__ ssrc,
                               int* __restrict__ sdst) {
    const int e = blockIdx.x * 256 + threadIdx.x;      // NE exact
    const int d = ei[NE + e];
    const int p = atomicAdd(&cur[d], 1);
    sidx[p] = e; ssrc[p] = ei[e]; sdst[p] = d;
}

// dist in SORTED edge order
__global__ void dist_kernel(const float* __restrict__ pos, const int* __restrict__ sidx,
                            const int* __restrict__ ssrc, const int* __restrict__ sdst,
                            const float* __restrict__ cell, const float* __restrict__ U,
                            float* __restrict__ dist) {
    const int p = blockIdx.x * 256 + threadIdx.x;      // NE exact
    const int e = sidx[p];
    const int s = ssrc[p], d = sdst[p];
    const float c0 = cell[e*3], c1 = cell[e*3+1], c2 = cell[e*3+2];
    const float ox = c0*U[0] + c1*U[3] + c2*U[6];
    const float oy = c0*U[1] + c1*U[4] + c2*U[7];
    const float oz = c0*U[2] + c1*U[5] + c2*U[8];
    const float dx = pos[d*3]   - ox - pos[s*3];
    const float dy = pos[d*3+1] - oy - pos[s*3+1];
    const float dz = pos[d*3+2] - oz - pos[s*3+2];
    dist[p] = sqrtf(dx*dx + dy*dy + dz*dz);
}

// ---------------------------------------------------------------------------
// Edge MLP, dst-sorted, 128 edges/block, 4 waves x 32 rows. A-frags straight
// from global. t1/msg stored in LDS in p-space ([row][p(n)]) so each lane
// writes its 8 feats as ONE ds_write_b128 (4 x v_cvt_pk_bf16_f32).
// LDS exactly 32KB -> 5 blocks/CU.
// ---------------------------------------------------------------------------
__global__ __launch_bounds__(256, 2) void edge_kernel(
    const unsigned short* __restrict__ hb, const float* __restrict__ dist,
    const int* __restrict__ ssrc, const int* __restrict__ sdst,
    const unsigned short* __restrict__ pw,
    const float* __restrict__ w1last, const float* __restrict__ b1,
    const float* __restrict__ g1, const float* __restrict__ be1,
    const float* __restrict__ b2, const float* __restrict__ g2,
    const float* __restrict__ be2, float* __restrict__ aggr)
{
    __shared__ unsigned short lds[128 * 128];          // 32KB: [row][p-feat]
    char* ldsb = (char*)lds;
    const int tid = threadIdx.x, blk = blockIdx.x;
    const int l = tid & 63, wv = tid >> 6;
    const int li = l & 15, gq = l >> 4;

    const int rowA = wv*32 + li, rowB = rowA + 16;
    const int eA = blk*128 + rowA, eB = blk*128 + rowB;
    const unsigned short* pDA = hb + sdst[eA]*HD + gq*8;
    const unsigned short* pSA = hb + ssrc[eA]*HD + gq*8;
    const unsigned short* pDB = hb + sdst[eB]*HD + gq*8;
    const unsigned short* pSB = hb + ssrc[eB]*HD + gq*8;

    f4 acc[2][8];
    #pragma unroll
    for (int m = 0; m < 2; ++m)
        #pragma unroll
        for (int f = 0; f < 8; ++f) { f4 z = {0.f,0.f,0.f,0.f}; acc[m][f] = z; }

    #pragma unroll
    for (int s = 0; s < 8; ++s) {
        bf8 breg[8];
        #pragma unroll
        for (int f = 0; f < 8; ++f) breg[f] = *(const bf8*)(pw + s*4096 + f*512 + l*8);
        const bf8 aA = (s < 4) ? *(const bf8*)(pDA + s*32) : *(const bf8*)(pSA + (s-4)*32);
        const bf8 aB = (s < 4) ? *(const bf8*)(pDB + s*32) : *(const bf8*)(pSB + (s-4)*32);
        #pragma unroll
        for (int f = 0; f < 8; ++f) {
            acc[0][f] = __builtin_amdgcn_mfma_f32_16x16x32_bf16(aA, breg[f], acc[0][f], 0, 0, 0);
            acc[1][f] = __builtin_amdgcn_mfma_f32_16x16x32_bf16(aB, breg[f], acc[1][f], 0, 0, 0);
        }
    }

    // epilogue 1: acc += b1 + dist*w1last (in-place) -> LN -> relu -> b128 p-space write
    {
        float bb[8], wl[8], gg[8], be[8];
        #pragma unroll
        for (int f = 0; f < 8; ++f) {
            const int n = f*16 + li;
            bb[f] = b1[n]; wl[f] = w1last[n]; gg[f] = g1[n]; be[f] = be1[n];
        }
        #pragma unroll
        for (int m = 0; m < 2; ++m) {
            const float4 d4 = *(const float4*)(dist + blk*128 + wv*32 + m*16 + gq*4);
            const float dsv[4] = {d4.x, d4.y, d4.z, d4.w};
            float ps[4] = {0,0,0,0}, pq[4] = {0,0,0,0};
            #pragma unroll
            for (int f = 0; f < 8; ++f)
                #pragma unroll
                for (int r = 0; r < 4; ++r) {
                    const float v = acc[m][f][r] + bb[f] + dsv[r]*wl[f];
                    acc[m][f][r] = v;
                    ps[r] += v; pq[r] += v*v;
                }
            #pragma unroll
            for (int mm = 1; mm < 16; mm <<= 1)
                #pragma unroll
                for (int r = 0; r < 4; ++r) {
                    ps[r] += __shfl_xor(ps[r], mm);
                    pq[r] += __shfl_xor(pq[r], mm);
                }
            #pragma unroll
            for (int r = 0; r < 4; ++r) {
                const float mean = ps[r] * (1.f/HD);
                const float rstd = rsqrtf(pq[r]*(1.f/HD) - mean*mean + LNEPS);
                const int row = wv*32 + m*16 + gq*4 + r;
                float vv[8];
                #pragma unroll
                for (int f = 0; f < 8; ++f)
                    vv[f] = fmaxf((acc[m][f][r] - mean)*rstd*gg[f] + be[f], 0.f);
                uint4 u;
                u.x = cvt2bf(vv[0], vv[1]); u.y = cvt2bf(vv[2], vv[3]);
                u.z = cvt2bf(vv[4], vv[5]); u.w = cvt2bf(vv[6], vv[7]);
                *(uint4*)(ldsb + ((row*256 + li*16) ^ ((row & 7) << 4))) = u;
            }
        }
    }
    // rows are wave-private: no barrier before GEMM2

    const unsigned short* pw2 = pw + 32768;
    f4 acc2[2][8];
    #pragma unroll
    for (int m = 0; m < 2; ++m)
        #pragma unroll
        for (int f = 0; f < 8; ++f) { f4 z = {0.f,0.f,0.f,0.f}; acc2[m][f] = z; }
    #pragma unroll
    for (int s = 0; s < 4; ++s) {
        bf8 breg[8];
        #pragma unroll
        for (int f = 0; f < 8; ++f) breg[f] = *(const bf8*)(pw2 + s*4096 + f*512 + l*8);
        #pragma unroll
        for (int m = 0; m < 2; ++m) {
            const int ar = wv*32 + m*16 + li;
            const bf8 a = *(const bf8*)(ldsb + ((ar*256 + s*64 + gq*16) ^ ((ar & 7) << 4)));
            #pragma unroll
            for (int f = 0; f < 8; ++f)
                acc2[m][f] = __builtin_amdgcn_mfma_f32_16x16x32_bf16(a, breg[f], acc2[m][f], 0, 0, 0);
        }
    }

    // epilogue 2: +b2 (in-place) -> LN -> relu -> b128 p-space msg write
    {
        float bb2[8], gg2[8], be2v[8];
        #pragma unroll
        for (int f = 0; f < 8; ++f) {
            const int n = f*16 + li;
            bb2[f] = b2[n]; gg2[f] = g2[n]; be2v[f] = be2[n];
        }
        #pragma unroll
        for (int m = 0; m < 2; ++m) {
            float ps[4] = {0,0,0,0}, pq[4] = {0,0,0,0};
            #pragma unroll
            for (int f = 0; f < 8; ++f)
                #pragma unroll
                for (int r = 0; r < 4; ++r) {
                    const float v = acc2[m][f][r] + bb2[f];
                    acc2[m][f][r] = v;
                    ps[r] += v; pq[r] += v*v;
                }
            #pragma unroll
            for (int mm = 1; mm < 16; mm <<= 1)
                #pragma unroll
                for (int r = 0; r < 4; ++r) {
                    ps[r] += __shfl_xor(ps[r], mm);
                    pq[r] += __shfl_xor(pq[r], mm);
                }
            #pragma unroll
            for (int r = 0; r < 4; ++r) {
                const float mean = ps[r] * (1.f/HD);
                const float rstd = rsqrtf(pq[r]*(1.f/HD) - mean*mean + LNEPS);
                const int row = wv*32 + m*16 + gq*4 + r;
                float vv[8];
                #pragma unroll
                for (int f = 0; f < 8; ++f)
                    vv[f] = fmaxf((acc2[m][f][r] - mean)*rstd*gg2[f] + be2v[f], 0.f);
                uint4 u;
                u.x = cvt2bf(vv[0], vv[1]); u.y = cvt2bf(vv[2], vv[3]);
                u.z = cvt2bf(vv[4], vv[5]); u.w = cvt2bf(vv[6], vv[7]);
                *(uint4*)(ldsb + ((row*256 + li*16) ^ ((row & 7) << 4))) = u;
            }
        }
    }
    __syncthreads();

    // segmented reduce over 128 sorted rows: thread = (p-col j, half hh)
    {
        const int j = tid & 127, hh = tid >> 7;
        const int r0 = hh * 64;
        const int jj = (j & 7)*16 + (j >> 3);          // original feature
        int curd = sdst[blk*128 + r0];
        float a0 = 0.f;
        #pragma unroll 4
        for (int i = 0; i < 64; ++i) {
            const int row = r0 + i;
            const int d = sdst[blk*128 + row];
            const unsigned short u = *(const unsigned short*)(ldsb + ((row*256 + j*2) ^ ((row & 7) << 4)));
            const float v = __uint_as_float(((unsigned int)u) << 16);
            if (d != curd) { unsafeAtomicAdd(&aggr[curd*HD + jj], a0); a0 = 0.f; curd = d; }
            a0 += v;
        }
        unsafeAtomicAdd(&aggr[curd*HD + jj], a0);
    }
}

// ---------------------------------------------------------------------------
// Node update, 128 nodes/block. Same p-space t1 trick. Zeroes aggr in-place.
// ---------------------------------------------------------------------------
__global__ __launch_bounds__(256, 2) void node_kernel(
    unsigned short* __restrict__ hb, float* __restrict__ aggr,
    const unsigned short* __restrict__ pw,
    const float* __restrict__ b1, const float* __restrict__ g1, const float* __restrict__ be1,
    const float* __restrict__ b2, const float* __restrict__ g2, const float* __restrict__ be2,
    float* __restrict__ h)
{
    __shared__ unsigned short lds[128 * 128];
    char* ldsb = (char*)lds;
    const int tid = threadIdx.x, blk = blockIdx.x;
    const int l = tid & 63, wv = tid >> 6;
    const int li = l & 15, gq = l >> 4;

    const int rowA = wv*32 + li, rowB = rowA + 16;
    const int nA = blk*128 + rowA, nB = blk*128 + rowB;
    const int ncA = (nA < NN) ? nA : NN - 1;
    const int ncB = (nB < NN) ? nB : NN - 1;
    const unsigned short* pHA = hb + ncA*HD + gq*8;
    const unsigned short* pHB = hb + ncB*HD + gq*8;
    float* pAA = aggr + ncA*HD + gq*8;
    float* pAB = aggr + ncB*HD + gq*8;

    f4 acc[2][8];
    #pragma unroll
    for (int m = 0; m < 2; ++m)
        #pragma unroll
        for (int f = 0; f < 8; ++f) { f4 z = {0.f,0.f,0.f,0.f}; acc[m][f] = z; }

    #pragma unroll
    for (int s = 0; s < 8; ++s) {
        bf8 breg[8];
        #pragma unroll
        for (int f = 0; f < 8; ++f) breg[f] = *(const bf8*)(pw + s*4096 + f*512 + l*8);
        bf8 aA, aB;
        if (s < 4) {
            aA = *(const bf8*)(pHA + s*32);
            aB = *(const bf8*)(pHB + s*32);
        } else {
            const float4 a0 = *(const float4*)(pAA + (s-4)*32);
            const float4 a1 = *(const float4*)(pAA + (s-4)*32 + 4);
            const float4 c0 = *(const float4*)(pAB + (s-4)*32);
            const float4 c1 = *(const float4*)(pAB + (s-4)*32 + 4);
            union { unsigned int u[4]; bf8 v; } pk;
            pk.u[0] = cvt2bf(a0.x, a0.y); pk.u[1] = cvt2bf(a0.z, a0.w);
            pk.u[2] = cvt2bf(a1.x, a1.y); pk.u[3] = cvt2bf(a1.z, a1.w);
            aA = pk.v;
            pk.u[0] = cvt2bf(c0.x, c0.y); pk.u[1] = cvt2bf(c0.z, c0.w);
            pk.u[2] = cvt2bf(c1.x, c1.y); pk.u[3] = cvt2bf(c1.z, c1.w);
            aB = pk.v;
        }
        #pragma unroll
        for (int f = 0; f < 8; ++f) {
            acc[0][f] = __builtin_amdgcn_mfma_f32_16x16x32_bf16(aA, breg[f], acc[0][f], 0, 0, 0);
            acc[1][f] = __builtin_amdgcn_mfma_f32_16x16x32_bf16(aB, breg[f], acc[1][f], 0, 0, 0);
        }
    }

    // zero aggr slices for next layer (loads consumed above)
    {
        const float4 z = {0.f,0.f,0.f,0.f};
        #pragma unroll
        for (int s = 0; s < 4; ++s) {
            if (nA < NN) { *(float4*)(pAA + s*32) = z; *(float4*)(pAA + s*32 + 4) = z; }
            if (nB < NN) { *(float4*)(pAB + s*32) = z; *(float4*)(pAB + s*32 + 4) = z; }
        }
    }

    // epilogue 1 -> p-space t1
    {
        float bb[8], gg[8], be[8];
        #pragma unroll
        for (int f = 0; f < 8; ++f) {
            const int n = f*16 + li;
            bb[f] = b1[n]; gg[f] = g1[n]; be[f] = be1[n];
        }
        #pragma unroll
        for (int m = 0; m < 2; ++m) {
            float ps[4] = {0,0,0,0}, pq[4] = {0,0,0,0};
            #pragma unroll
            for (int f = 0; f < 8; ++f)
                #pragma unroll
                for (int r = 0; r < 4; ++r) {
                    const float v = acc[m][f][r] + bb[f];
                    acc[m][f][r] = v;
                    ps[r] += v; pq[r] += v*v;
                }
            #pragma unroll
            for (int mm = 1; mm < 16; mm <<= 1)
                #pragma unroll
                for (int r = 0; r < 4; ++r) {
                    ps[r] += __shfl_xor(ps[r], mm);
                    pq[r] += __shfl_xor(pq[r], mm);
                }
            #pragma unroll
            for (int r = 0; r < 4; ++r) {
                const float mean = ps[r] * (1.f/HD);
                const float rstd = rsqrtf(pq[r]*(1.f/HD) - mean*mean + LNEPS);
                const int row = wv*32 + m*16 + gq*4 + r;
                float vv[8];
                #pragma unroll
                for (int f = 0; f < 8; ++f)
                    vv[f] = fmaxf((acc[m][f][r] - mean)*rstd*gg[f] + be[f], 0.f);
                uint4 u;
                u.x = cvt2bf(vv[0], vv[1]); u.y = cvt2bf(vv[2], vv[3]);
                u.z = cvt2bf(vv[4], vv[5]); u.w = cvt2bf(vv[6], vv[7]);
                *(uint4*)(ldsb + ((row*256 + li*16) ^ ((row & 7) << 4))) = u;
            }
        }
    }

    const unsigned short* pw2 = pw + 32768;
    f4 acc2[2][8];
    #pragma unroll
    for (int m = 0; m < 2; ++m)
        #pragma unroll
        for (int f = 0; f < 8; ++f) { f4 z = {0.f,0.f,0.f,0.f}; acc2[m][f] = z; }
    #pragma unroll
    for (int s = 0; s < 4; ++s) {
        bf8 breg[8];
        #pragma unroll
        for (int f = 0; f < 8; ++f) breg[f] = *(const bf8*)(pw2 + s*4096 + f*512 + l*8);
        #pragma unroll
        for (int m = 0; m < 2; ++m) {
            const int ar = wv*32 + m*16 + li;
            const bf8 a = *(const bf8*)(ldsb + ((ar*256 + s*64 + gq*16) ^ ((ar & 7) << 4)));
            #pragma unroll
            for (int f = 0; f < 8; ++f)
                acc2[m][f] = __builtin_amdgcn_mfma_f32_16x16x32_bf16(a, breg[f], acc2[m][f], 0, 0, 0);
        }
    }

    // epilogue 2: LN -> relu -> residual h += u, refresh hb
    {
        float bb2[8], gg2[8], be2v[8];
        #pragma unroll
        for (int f = 0; f < 8; ++f) {
            const int n = f*16 + li;
            bb2[f] = b2[n]; gg2[f] = g2[n]; be2v[f] = be2[n];
        }
        #pragma unroll
        for (int m = 0; m < 2; ++m) {
            float ps[4] = {0,0,0,0}, pq[4] = {0,0,0,0};
            #pragma unroll
            for (int f = 0; f < 8; ++f)
                #pragma unroll
                for (int r = 0; r < 4; ++r) {
                    const float v = acc2[m][f][r] + bb2[f];
                    acc2[m][f][r] = v;
                    ps[r] += v; pq[r] += v*v;
                }
            #pragma unroll
            for (int mm = 1; mm < 16; mm <<= 1)
                #pragma unroll
                for (int r = 0; r < 4; ++r) {
                    ps[r] += __shfl_xor(ps[r], mm);
                    pq[r] += __shfl_xor(pq[r], mm);
                }
            #pragma unroll
            for (int r = 0; r < 4; ++r) {
                const int node = blk*128 + wv*32 + m*16 + gq*4 + r;
                if (node < NN) {
                    const float mean = ps[r] * (1.f/HD);
                    const float rstd = rsqrtf(pq[r]*(1.f/HD) - mean*mean + LNEPS);
                    #pragma unroll
                    for (int f = 0; f < 8; ++f) {
                        const int n = f*16 + li;
                        float v = (acc2[m][f][r] - mean)*rstd*gg2[f] + be2v[f];
                        v = fmaxf(v, 0.f);
                        const int idx = node*HD + n;
                        const float nh = h[idx] + v;
                        h[idx] = nh;
                        hb[idx] = bf1(nh);
                    }
                }
            }
        }
    }
}

// global_add_pool over sorted batch_ids
__global__ void pool_kernel(const float* __restrict__ h, const int* __restrict__ bids,
                            float* __restrict__ pooled) {
    const int j = threadIdx.x;                  // 128 features
    const int n0 = blockIdx.x * 256;
    if (n0 >= NN) return;
    int cur = bids[n0];
    float acc = 0.f;
    for (int i = 0; i < 256; ++i) {
        const int n = n0 + i;
        if (n >= NN) break;
        const int b = bids[n];
        if (b != cur) { unsafeAtomicAdd(&pooled[cur*HD + j], acc); acc = 0.f; cur = b; }
        acc += h[n*HD + j];
    }
    unsafeAtomicAdd(&pooled[cur*HD + j], acc);
}

__global__ void pred_kernel(const float* __restrict__ pooled, const float* __restrict__ w1,
                            const float* __restrict__ pb1, const float* __restrict__ w2,
                            const float* __restrict__ pb2, float* __restrict__ out) {
    const int g = blockIdx.x, j = threadIdx.x;  // 128 threads
    __shared__ float pg[128];
    __shared__ float red[128];
    pg[j] = pooled[g*HD + j];
    __syncthreads();
    float z = pb1[j];
    for (int k = 0; k < 128; ++k) z += pg[k] * w1[k*HD + j];
    red[j] = fmaxf(z, 0.f) * w2[j];
    __syncthreads();
    for (int st = 64; st > 0; st >>= 1) {
        if (j < st) red[j] += red[j + st];
        __syncthreads();
    }
    if (j == 0) out[g] = red[0] + pb2[0];
}

extern "C" void kernel_launch(void* const* d_in, const int* in_sizes, int n_in,
                              void* d_out, int out_size, void* d_ws, size_t ws_size,
                              hipStream_t stream) {
    const float* x       = (const float*)d_in[0];
    const float* pos     = (const float*)d_in[1];
    const int*   ei      = (const int*)  d_in[2];
    const float* cell    = (const float*)d_in[3];
    const float* U       = (const float*)d_in[4];
    const int*   bids    = (const int*)  d_in[5];
    const float* emb_w   = (const float*)d_in[6];
    const float* emb_b   = (const float*)d_in[7];
    const float* msg_w1  = (const float*)d_in[8];
    const float* msg_b1  = (const float*)d_in[9];
    const float* msg_g1  = (const float*)d_in[10];
    const float* msg_be1 = (const float*)d_in[11];
    const float* msg_w2  = (const float*)d_in[12];
    const float* msg_b2  = (const float*)d_in[13];
    const float* msg_g2  = (const float*)d_in[14];
    const float* msg_be2 = (const float*)d_in[15];
    const float* upd_w1  = (const float*)d_in[16];
    const float* upd_b1  = (const float*)d_in[17];
    const float* upd_g1  = (const float*)d_in[18];
    const float* upd_be1 = (const float*)d_in[19];
    const float* upd_w2  = (const float*)d_in[20];
    const float* upd_b2  = (const float*)d_in[21];
    const float* upd_g2  = (const float*)d_in[22];
    const float* upd_be2 = (const float*)d_in[23];
    const float* pred_w1 = (const float*)d_in[24];
    const float* pred_b1 = (const float*)d_in[25];
    const float* pred_w2 = (const float*)d_in[26];
    const float* pred_b2 = (const float*)d_in[27];

    char* ws = (char*)d_ws;
    float*          h      = (float*)          ws;                 // 25,600,000
    unsigned short* hb     = (unsigned short*)(ws + 25600000);     // 12,800,000
    float*          aggr   = (float*)         (ws + 38400000);     // 25,600,000
    float*          dist   = (float*)         (ws + 64000000);     //  3,200,000
    float*          pooled = (float*)         (ws + 67200000);     //     32,768
    unsigned short* packed = (unsigned short*)(ws + 67232768);     //    983,040
    int*            cnt    = (int*)           (ws + 68215808);     //    200,704
    int*            cur    = (int*)           (ws + 68416512);     //    200,704
    int*            sidx   = (int*)           (ws + 68617216);     //  3,200,000
    int*            ssrc   = (int*)           (ws + 71817216);     //  3,200,000
    int*            sdst   = (int*)           (ws + 75017216);     //  3,200,000

    hipMemsetAsync(aggr, 0, (size_t)NN * HD * sizeof(float), stream);
    hipMemsetAsync(pooled, 0, (size_t)NG * HD * sizeof(float), stream);
    hipMemsetAsync(cnt, 0, (size_t)NN * sizeof(int), stream);

    dim3 pgrid(128, DEPTH * 4);
    pack_weights<<<pgrid, 256, 0, stream>>>(msg_w1, msg_w2, upd_w1, upd_w2, packed);
    embed_kernel<<<(NN * HD) / 256, 256, 0, stream>>>(x, emb_w, emb_b, h, hb);

    hist_kernel<<<NE / 256, 256, 0, stream>>>(ei, cnt);
    scan_kernel<<<1, 1024, 0, stream>>>(cnt, cur);
    scatter_kernel<<<NE / 256, 256, 0, stream>>>(ei, cur, sidx, ssrc, sdst);
    dist_kernel<<<NE / 256, 256, 0, stream>>>(pos, sidx, ssrc, sdst, cell, U, dist);

    for (int layer = 0; layer < DEPTH; ++layer) {
        const unsigned short* pl = packed + layer * 98304;
        edge_kernel<<<NE / 128, 256, 0, stream>>>(
            hb, dist, ssrc, sdst, pl,
            msg_w1 + layer*257*HD + 256*HD,
            msg_b1 + layer*HD, msg_g1 + layer*HD, msg_be1 + layer*HD,
            msg_b2 + layer*HD, msg_g2 + layer*HD, msg_be2 + layer*HD,
            aggr);
        node_kernel<<<(NN + 127) / 128, 256, 0, stream>>>(
            hb, aggr, pl + 49152,
            upd_b1 + layer*HD, upd_g1 + layer*HD, upd_be1 + layer*HD,
            upd_b2 + layer*HD, upd_g2 + layer*HD, upd_be2 + layer*HD,
            h);
    }

    pool_kernel<<<(NN + 255) / 256, 128, 0, stream>>>(h, bids, pooled);
    pred_kernel<<<NG, 128, 0, stream>>>(pooled, pred_w1, pred_b1, pred_w2, pred_b2, (float*)d_out);
}

// Round 7
// 1489.090 us; speedup vs baseline: 1.2593x; 1.2593x over previous
//
#include <hip/hip_runtime.h>
#include <hip/hip_bf16.h>

#define NN 50000
#define NE 800000
#define HD 128
#define DEPTH 5
#define NG 64
#define LNEPS 1e-5f

typedef __attribute__((ext_vector_type(8))) short bf8;   // 8 x bf16
typedef __attribute__((ext_vector_type(4))) float f4;

// compiler-scheduled RNE conversions (m240: do NOT hand-write cvt_pk asm)
static __device__ __forceinline__ unsigned short bf1(float x) {
    __hip_bfloat16 b = __float2bfloat16(x);
    unsigned short r;
    __builtin_memcpy(&r, &b, 2);
    return r;
}
static __device__ __forceinline__ unsigned int cvt2(float a, float b) {
    float2 t; t.x = a; t.y = b;
    __hip_bfloat162 h = __float22bfloat162_rn(t);
    unsigned int r;
    __builtin_memcpy(&r, &h, 4);
    return r;
}

// ---------------------------------------------------------------------------
// Pack weights (K x 128 f32 row-major) into bf16 MFMA B-fragment layout:
// packed[s*4096 + f*512 + lane*8 + e] = W[krow][f*16 + (lane&15)],
// krow = s*32 + (lane>>4)*8 + e, except for the K=128 second-layer mats
// (which&1): krow = pinv(k) = (k&7)*16 + (k>>3) — matches the p-space t1
// layout (p(n) = (n&15)*8 + (n>>4)) used for the GEMM2 A-operand.
// ---------------------------------------------------------------------------
__global__ void pack_weights(const float* __restrict__ msg_w1, const float* __restrict__ msg_w2,
                             const float* __restrict__ upd_w1, const float* __restrict__ upd_w2,
                             unsigned short* __restrict__ packed) {
    const int which = blockIdx.y & 3, layer = blockIdx.y >> 2;
    const int t = blockIdx.x * 256 + threadIdx.x;
    const float* src; int K; unsigned short* dst;
    unsigned short* lbase = packed + layer * 98304;
    if (which == 0)      { src = msg_w1 + layer*257*HD; K = 256; dst = lbase; }
    else if (which == 1) { src = msg_w2 + layer*HD*HD;  K = 128; dst = lbase + 32768; }
    else if (which == 2) { src = upd_w1 + layer*256*HD; K = 256; dst = lbase + 49152; }
    else                 { src = upd_w2 + layer*HD*HD;  K = 128; dst = lbase + 81920; }
    if (t >= K * HD) return;
    const int e = t & 7, l = (t >> 3) & 63, f = (t >> 9) & 7, s = t >> 12;
    const int kk = s*32 + ((l >> 4) << 3) + e;
    const int k = (which & 1) ? ((kk & 7)*16 + (kk >> 3)) : kk;   // pinv for layer-2 mats
    const int n = f*16 + (l & 15);
    dst[t] = bf1(src[k*HD + n]);
}

__global__ void embed_kernel(const float* __restrict__ x, const float* __restrict__ emb_w,
                             const float* __restrict__ emb_b,
                             float* __restrict__ h, unsigned short* __restrict__ hb) {
    const int i = blockIdx.x * 256 + threadIdx.x;      // N*H exact
    const int n = i >> 7, j = i & 127;
    const float v = x[n] * emb_w[j] + emb_b[j];
    h[i] = v; hb[i] = bf1(v);
}

// --------------------- counting sort of edges by dst -----------------------
__global__ void hist_kernel(const int* __restrict__ ei, int* __restrict__ cnt) {
    const int e = blockIdx.x * 256 + threadIdx.x;      // NE exact
    atomicAdd(&cnt[ei[NE + e]], 1);
}

__global__ __launch_bounds__(1024) void scan_kernel(const int* __restrict__ cnt,
                                                    int* __restrict__ cur) {
    __shared__ int part[1024];
    const int t = threadIdx.x;
    const int per = 49;                                 // 1024*49 >= NN
    const int base = t * per;
    int s = 0;
    for (int i = 0; i < per; ++i) { const int idx = base + i; if (idx < NN) s += cnt[idx]; }
    part[t] = s; __syncthreads();
    for (int st = 1; st < 1024; st <<= 1) {
        const int v = (t >= st) ? part[t - st] : 0;
        __syncthreads();
        part[t] += v;
        __syncthreads();
    }
    int run = (t == 0) ? 0 : part[t - 1];
    for (int i = 0; i < per; ++i) {
        const int idx = base + i;
        if (idx < NN) { cur[idx] = run; run += cnt[idx]; }
    }
}

__global__ void scatter_kernel(const int* __restrict__ ei, int* __restrict__ cur,
                               int* __restrict__ sidx, int* __restrict__ ssrc,
                               int* __restrict__ sdst) {
    const int e = blockIdx.x * 256 + threadIdx.x;      // NE exact
    const int d = ei[NE + e];
    const int p = atomicAdd(&cur[d], 1);
    sidx[p] = e; ssrc[p] = ei[e]; sdst[p] = d;
}

// dist in SORTED edge order
__global__ void dist_kernel(const float* __restrict__ pos, const int* __restrict__ sidx,
                            const int* __restrict__ ssrc, const int* __restrict__ sdst,
                            const float* __restrict__ cell, const float* __restrict__ U,
                            float* __restrict__ dist) {
    const int p = blockIdx.x * 256 + threadIdx.x;      // NE exact
    const int e = sidx[p];
    const int s = ssrc[p], d = sdst[p];
    const float c0 = cell[e*3], c1 = cell[e*3+1], c2 = cell[e*3+2];
    const float ox = c0*U[0] + c1*U[3] + c2*U[6];
    const float oy = c0*U[1] + c1*U[4] + c2*U[7];
    const float oz = c0*U[2] + c1*U[5] + c2*U[8];
    const float dx = pos[d*3]   - ox - pos[s*3];
    const float dy = pos[d*3+1] - oy - pos[s*3+1];
    const float dz = pos[d*3+2] - oz - pos[s*3+2];
    dist[p] = sqrtf(dx*dx + dy*dy + dz*dz);
}

// ---------------------------------------------------------------------------
// Edge MLP, dst-sorted, 128 edges/block, 4 waves x 32 rows. A-frags straight
// from global. t1/msg in LDS in p-space so each lane writes its 8 feats as
// ONE ds_write_b128 built from 4 v_cvt_pk_bf16_f32 (intrinsic, not asm).
// ---------------------------------------------------------------------------
__global__ __launch_bounds__(256, 2) void edge_kernel(
    const unsigned short* __restrict__ hb, const float* __restrict__ dist,
    const int* __restrict__ ssrc, const int* __restrict__ sdst,
    const unsigned short* __restrict__ pw,
    const float* __restrict__ w1last, const float* __restrict__ b1,
    const float* __restrict__ g1, const float* __restrict__ be1,
    const float* __restrict__ b2, const float* __restrict__ g2,
    const float* __restrict__ be2, float* __restrict__ aggr)
{
    __shared__ unsigned short lds[128 * 128];          // 32KB: [row][p-feat]
    __shared__ int dstl[128];
    char* ldsb = (char*)lds;
    const int tid = threadIdx.x, blk = blockIdx.x;
    const int l = tid & 63, wv = tid >> 6;
    const int li = l & 15, gq = l >> 4;

    if (tid < 128) dstl[tid] = sdst[blk*128 + tid];

    const int rowA = wv*32 + li, rowB = rowA + 16;
    const int eA = blk*128 + rowA, eB = blk*128 + rowB;
    const unsigned short* pDA = hb + sdst[eA]*HD + gq*8;
    const unsigned short* pSA = hb + ssrc[eA]*HD + gq*8;
    const unsigned short* pDB = hb + sdst[eB]*HD + gq*8;
    const unsigned short* pSB = hb + ssrc[eB]*HD + gq*8;

    f4 acc[2][8];
    #pragma unroll
    for (int m = 0; m < 2; ++m)
        #pragma unroll
        for (int f = 0; f < 8; ++f) { f4 z = {0.f,0.f,0.f,0.f}; acc[m][f] = z; }

    #pragma unroll
    for (int s = 0; s < 8; ++s) {
        bf8 breg[8];
        #pragma unroll
        for (int f = 0; f < 8; ++f) breg[f] = *(const bf8*)(pw + s*4096 + f*512 + l*8);
        const bf8 aA = (s < 4) ? *(const bf8*)(pDA + s*32) : *(const bf8*)(pSA + (s-4)*32);
        const bf8 aB = (s < 4) ? *(const bf8*)(pDB + s*32) : *(const bf8*)(pSB + (s-4)*32);
        #pragma unroll
        for (int f = 0; f < 8; ++f) {
            acc[0][f] = __builtin_amdgcn_mfma_f32_16x16x32_bf16(aA, breg[f], acc[0][f], 0, 0, 0);
            acc[1][f] = __builtin_amdgcn_mfma_f32_16x16x32_bf16(aB, breg[f], acc[1][f], 0, 0, 0);
        }
    }

    // epilogue 1: acc += b1 + dist*w1last (in-place) -> LN -> relu -> b128 p-space write
    {
        float bb[8], wl[8], gg[8], be[8];
        #pragma unroll
        for (int f = 0; f < 8; ++f) {
            const int n = f*16 + li;
            bb[f] = b1[n]; wl[f] = w1last[n]; gg[f] = g1[n]; be[f] = be1[n];
        }
        #pragma unroll
        for (int m = 0; m < 2; ++m) {
            const float4 d4 = *(const float4*)(dist + blk*128 + wv*32 + m*16 + gq*4);
            const float dsv[4] = {d4.x, d4.y, d4.z, d4.w};
            float ps[4] = {0,0,0,0}, pq[4] = {0,0,0,0};
            #pragma unroll
            for (int f = 0; f < 8; ++f)
                #pragma unroll
                for (int r = 0; r < 4; ++r) {
                    const float v = acc[m][f][r] + bb[f] + dsv[r]*wl[f];
                    acc[m][f][r] = v;
                    ps[r] += v; pq[r] += v*v;
                }
            #pragma unroll
            for (int mm = 1; mm < 16; mm <<= 1)
                #pragma unroll
                for (int r = 0; r < 4; ++r) {
                    ps[r] += __shfl_xor(ps[r], mm);
                    pq[r] += __shfl_xor(pq[r], mm);
                }
            #pragma unroll
            for (int r = 0; r < 4; ++r) {
                const float mean = ps[r] * (1.f/HD);
                const float rstd = rsqrtf(pq[r]*(1.f/HD) - mean*mean + LNEPS);
                const int row = wv*32 + m*16 + gq*4 + r;
                float vv[8];
                #pragma unroll
                for (int f = 0; f < 8; ++f)
                    vv[f] = fmaxf((acc[m][f][r] - mean)*rstd*gg[f] + be[f], 0.f);
                uint4 u;
                u.x = cvt2(vv[0], vv[1]); u.y = cvt2(vv[2], vv[3]);
                u.z = cvt2(vv[4], vv[5]); u.w = cvt2(vv[6], vv[7]);
                *(uint4*)(ldsb + ((row*256 + li*16) ^ ((row & 7) << 4))) = u;
            }
        }
    }
    // rows are wave-private: no barrier before GEMM2

    const unsigned short* pw2 = pw + 32768;
    f4 acc2[2][8];
    #pragma unroll
    for (int m = 0; m < 2; ++m)
        #pragma unroll
        for (int f = 0; f < 8; ++f) { f4 z = {0.f,0.f,0.f,0.f}; acc2[m][f] = z; }
    #pragma unroll
    for (int s = 0; s < 4; ++s) {
        bf8 breg[8];
        #pragma unroll
        for (int f = 0; f < 8; ++f) breg[f] = *(const bf8*)(pw2 + s*4096 + f*512 + l*8);
        #pragma unroll
        for (int m = 0; m < 2; ++m) {
            const int ar = wv*32 + m*16 + li;
            const bf8 a = *(const bf8*)(ldsb + ((ar*256 + s*64 + gq*16) ^ ((ar & 7) << 4)));
            #pragma unroll
            for (int f = 0; f < 8; ++f)
                acc2[m][f] = __builtin_amdgcn_mfma_f32_16x16x32_bf16(a, breg[f], acc2[m][f], 0, 0, 0);
        }
    }

    // epilogue 2: +b2 (in-place) -> LN -> relu -> b128 p-space msg write
    {
        float bb2[8], gg2[8], be2v[8];
        #pragma unroll
        for (int f = 0; f < 8; ++f) {
            const int n = f*16 + li;
            bb2[f] = b2[n]; gg2[f] = g2[n]; be2v[f] = be2[n];
        }
        #pragma unroll
        for (int m = 0; m < 2; ++m) {
            float ps[4] = {0,0,0,0}, pq[4] = {0,0,0,0};
            #pragma unroll
            for (int f = 0; f < 8; ++f)
                #pragma unroll
                for (int r = 0; r < 4; ++r) {
                    const float v = acc2[m][f][r] + bb2[f];
                    acc2[m][f][r] = v;
                    ps[r] += v; pq[r] += v*v;
                }
            #pragma unroll
            for (int mm = 1; mm < 16; mm <<= 1)
                #pragma unroll
                for (int r = 0; r < 4; ++r) {
                    ps[r] += __shfl_xor(ps[r], mm);
                    pq[r] += __shfl_xor(pq[r], mm);
                }
            #pragma unroll
            for (int r = 0; r < 4; ++r) {
                const float mean = ps[r] * (1.f/HD);
                const float rstd = rsqrtf(pq[r]*(1.f/HD) - mean*mean + LNEPS);
                const int row = wv*32 + m*16 + gq*4 + r;
                float vv[8];
                #pragma unroll
                for (int f = 0; f < 8; ++f)
                    vv[f] = fmaxf((acc2[m][f][r] - mean)*rstd*gg2[f] + be2v[f], 0.f);
                uint4 u;
                u.x = cvt2(vv[0], vv[1]); u.y = cvt2(vv[2], vv[3]);
                u.z = cvt2(vv[4], vv[5]); u.w = cvt2(vv[6], vv[7]);
                *(uint4*)(ldsb + ((row*256 + li*16) ^ ((row & 7) << 4))) = u;
            }
        }
    }
    __syncthreads();

    // segmented reduce over 128 sorted rows: thread = (p-col j, half hh)
    {
        const int j = tid & 127, hh = tid >> 7;
        const int r0 = hh * 64;
        const int jj = (j & 7)*16 + (j >> 3);          // original feature
        int curd = dstl[r0];
        float a0 = 0.f;
        #pragma unroll 4
        for (int i = 0; i < 64; ++i) {
            const int row = r0 + i;
            const int d = dstl[row];
            const unsigned short u = *(const unsigned short*)(ldsb + ((row*256 + j*2) ^ ((row & 7) << 4)));
            const float v = __uint_as_float(((unsigned int)u) << 16);
            if (d != curd) { unsafeAtomicAdd(&aggr[curd*HD + jj], a0); a0 = 0.f; curd = d; }
            a0 += v;
        }
        unsafeAtomicAdd(&aggr[curd*HD + jj], a0);
    }
}

// ---------------------------------------------------------------------------
// Node update, 128 nodes/block. Same p-space t1 trick. Zeroes aggr in-place.
// ---------------------------------------------------------------------------
__global__ __launch_bounds__(256, 2) void node_kernel(
    unsigned short* __restrict__ hb, float* __restrict__ aggr,
    const unsigned short* __restrict__ pw,
    const float* __restrict__ b1, const float* __restrict__ g1, const float* __restrict__ be1,
    const float* __restrict__ b2, const float* __restrict__ g2, const float* __restrict__ be2,
    float* __restrict__ h)
{
    __shared__ unsigned short lds[128 * 128];
    char* ldsb = (char*)lds;
    const int tid = threadIdx.x, blk = blockIdx.x;
    const int l = tid & 63, wv = tid >> 6;
    const int li = l & 15, gq = l >> 4;

    const int rowA = wv*32 + li, rowB = rowA + 16;
    const int nA = blk*128 + rowA, nB = blk*128 + rowB;
    const int ncA = (nA < NN) ? nA : NN - 1;
    const int ncB = (nB < NN) ? nB : NN - 1;
    const unsigned short* pHA = hb + ncA*HD + gq*8;
    const unsigned short* pHB = hb + ncB*HD + gq*8;
    float* pAA = aggr + ncA*HD + gq*8;
    float* pAB = aggr + ncB*HD + gq*8;

    f4 acc[2][8];
    #pragma unroll
    for (int m = 0; m < 2; ++m)
        #pragma unroll
        for (int f = 0; f < 8; ++f) { f4 z = {0.f,0.f,0.f,0.f}; acc[m][f] = z; }

    #pragma unroll
    for (int s = 0; s < 8; ++s) {
        bf8 breg[8];
        #pragma unroll
        for (int f = 0; f < 8; ++f) breg[f] = *(const bf8*)(pw + s*4096 + f*512 + l*8);
        bf8 aA, aB;
        if (s < 4) {
            aA = *(const bf8*)(pHA + s*32);
            aB = *(const bf8*)(pHB + s*32);
        } else {
            const float4 a0 = *(const float4*)(pAA + (s-4)*32);
            const float4 a1 = *(const float4*)(pAA + (s-4)*32 + 4);
            const float4 c0 = *(const float4*)(pAB + (s-4)*32);
            const float4 c1 = *(const float4*)(pAB + (s-4)*32 + 4);
            union { unsigned int u[4]; bf8 v; } pk;
            pk.u[0] = cvt2(a0.x, a0.y); pk.u[1] = cvt2(a0.z, a0.w);
            pk.u[2] = cvt2(a1.x, a1.y); pk.u[3] = cvt2(a1.z, a1.w);
            aA = pk.v;
            pk.u[0] = cvt2(c0.x, c0.y); pk.u[1] = cvt2(c0.z, c0.w);
            pk.u[2] = cvt2(c1.x, c1.y); pk.u[3] = cvt2(c1.z, c1.w);
            aB = pk.v;
        }
        #pragma unroll
        for (int f = 0; f < 8; ++f) {
            acc[0][f] = __builtin_amdgcn_mfma_f32_16x16x32_bf16(aA, breg[f], acc[0][f], 0, 0, 0);
            acc[1][f] = __builtin_amdgcn_mfma_f32_16x16x32_bf16(aB, breg[f], acc[1][f], 0, 0, 0);
        }
    }

    // zero aggr slices for next layer (loads consumed above)
    {
        const float4 z = {0.f,0.f,0.f,0.f};
        #pragma unroll
        for (int s = 0; s < 4; ++s) {
            if (nA < NN) { *(float4*)(pAA + s*32) = z; *(float4*)(pAA + s*32 + 4) = z; }
            if (nB < NN) { *(float4*)(pAB + s*32) = z; *(float4*)(pAB + s*32 + 4) = z; }
        }
    }

    // epilogue 1 -> p-space t1
    {
        float bb[8], gg[8], be[8];
        #pragma unroll
        for (int f = 0; f < 8; ++f) {
            const int n = f*16 + li;
            bb[f] = b1[n]; gg[f] = g1[n]; be[f] = be1[n];
        }
        #pragma unroll
        for (int m = 0; m < 2; ++m) {
            float ps[4] = {0,0,0,0}, pq[4] = {0,0,0,0};
            #pragma unroll
            for (int f = 0; f < 8; ++f)
                #pragma unroll
                for (int r = 0; r < 4; ++r) {
                    const float v = acc[m][f][r] + bb[f];
                    acc[m][f][r] = v;
                    ps[r] += v; pq[r] += v*v;
                }
            #pragma unroll
            for (int mm = 1; mm < 16; mm <<= 1)
                #pragma unroll
                for (int r = 0; r < 4; ++r) {
                    ps[r] += __shfl_xor(ps[r], mm);
                    pq[r] += __shfl_xor(pq[r], mm);
                }
            #pragma unroll
            for (int r = 0; r < 4; ++r) {
                const float mean = ps[r] * (1.f/HD);
                const float rstd = rsqrtf(pq[r]*(1.f/HD) - mean*mean + LNEPS);
                const int row = wv*32 + m*16 + gq*4 + r;
                float vv[8];
                #pragma unroll
                for (int f = 0; f < 8; ++f)
                    vv[f] = fmaxf((acc[m][f][r] - mean)*rstd*gg[f] + be[f], 0.f);
                uint4 u;
                u.x = cvt2(vv[0], vv[1]); u.y = cvt2(vv[2], vv[3]);
                u.z = cvt2(vv[4], vv[5]); u.w = cvt2(vv[6], vv[7]);
                *(uint4*)(ldsb + ((row*256 + li*16) ^ ((row & 7) << 4))) = u;
            }
        }
    }

    const unsigned short* pw2 = pw + 32768;
    f4 acc2[2][8];
    #pragma unroll
    for (int m = 0; m < 2; ++m)
        #pragma unroll
        for (int f = 0; f < 8; ++f) { f4 z = {0.f,0.f,0.f,0.f}; acc2[m][f] = z; }
    #pragma unroll
    for (int s = 0; s < 4; ++s) {
        bf8 breg[8];
        #pragma unroll
        for (int f = 0; f < 8; ++f) breg[f] = *(const bf8*)(pw2 + s*4096 + f*512 + l*8);
        #pragma unroll
        for (int m = 0; m < 2; ++m) {
            const int ar = wv*32 + m*16 + li;
            const bf8 a = *(const bf8*)(ldsb + ((ar*256 + s*64 + gq*16) ^ ((ar & 7) << 4)));
            #pragma unroll
            for (int f = 0; f < 8; ++f)
                acc2[m][f] = __builtin_amdgcn_mfma_f32_16x16x32_bf16(a, breg[f], acc2[m][f], 0, 0, 0);
        }
    }

    // epilogue 2: LN -> relu -> residual h += u, refresh hb
    {
        float bb2[8], gg2[8], be2v[8];
        #pragma unroll
        for (int f = 0; f < 8; ++f) {
            const int n = f*16 + li;
            bb2[f] = b2[n]; gg2[f] = g2[n]; be2v[f] = be2[n];
        }
        #pragma unroll
        for (int m = 0; m < 2; ++m) {
            float ps[4] = {0,0,0,0}, pq[4] = {0,0,0,0};
            #pragma unroll
            for (int f = 0; f < 8; ++f)
                #pragma unroll
                for (int r = 0; r < 4; ++r) {
                    const float v = acc2[m][f][r] + bb2[f];
                    acc2[m][f][r] = v;
                    ps[r] += v; pq[r] += v*v;
                }
            #pragma unroll
            for (int mm = 1; mm < 16; mm <<= 1)
                #pragma unroll
                for (int r = 0; r < 4; ++r) {
                    ps[r] += __shfl_xor(ps[r], mm);
                    pq[r] += __shfl_xor(pq[r], mm);
                }
            #pragma unroll
            for (int r = 0; r < 4; ++r) {
                const int node = blk*128 + wv*32 + m*16 + gq*4 + r;
                if (node < NN) {
                    const float mean = ps[r] * (1.f/HD);
                    const float rstd = rsqrtf(pq[r]*(1.f/HD) - mean*mean + LNEPS);
                    #pragma unroll
                    for (int f = 0; f < 8; ++f) {
                        const int n = f*16 + li;
                        float v = (acc2[m][f][r] - mean)*rstd*gg2[f] + be2v[f];
                        v = fmaxf(v, 0.f);
                        const int idx = node*HD + n;
                        const float nh = h[idx] + v;
                        h[idx] = nh;
                        hb[idx] = bf1(nh);
                    }
                }
            }
        }
    }
}

// global_add_pool over sorted batch_ids
__global__ void pool_kernel(const float* __restrict__ h, const int* __restrict__ bids,
                            float* __restrict__ pooled) {
    const int j = threadIdx.x;                  // 128 features
    const int n0 = blockIdx.x * 256;
    if (n0 >= NN) return;
    int cur = bids[n0];
    float acc = 0.f;
    for (int i = 0; i < 256; ++i) {
        const int n = n0 + i;
        if (n >= NN) break;
        const int b = bids[n];
        if (b != cur) { unsafeAtomicAdd(&pooled[cur*HD + j], acc); acc = 0.f; cur = b; }
        acc += h[n*HD + j];
    }
    unsafeAtomicAdd(&pooled[cur*HD + j], acc);
}

__global__ void pred_kernel(const float* __restrict__ pooled, const float* __restrict__ w1,
                            const float* __restrict__ pb1, const float* __restrict__ w2,
                            const float* __restrict__ pb2, float* __restrict__ out) {
    const int g = blockIdx.x, j = threadIdx.x;  // 128 threads
    __shared__ float pg[128];
    __shared__ float red[128];
    pg[j] = pooled[g*HD + j];
    __syncthreads();
    float z = pb1[j];
    for (int k = 0; k < 128; ++k) z += pg[k] * w1[k*HD + j];
    red[j] = fmaxf(z, 0.f) * w2[j];
    __syncthreads();
    for (int st = 64; st > 0; st >>= 1) {
        if (j < st) red[j] += red[j + st];
        __syncthreads();
    }
    if (j == 0) out[g] = red[0] + pb2[0];
}

extern "C" void kernel_launch(void* const* d_in, const int* in_sizes, int n_in,
                              void* d_out, int out_size, void* d_ws, size_t ws_size,
                              hipStream_t stream) {
    const float* x       = (const float*)d_in[0];
    const float* pos     = (const float*)d_in[1];
    const int*   ei      = (const int*)  d_in[2];
    const float* cell    = (const float*)d_in[3];
    const float* U       = (const float*)d_in[4];
    const int*   bids    = (const int*)  d_in[5];
    const float* emb_w   = (const float*)d_in[6];
    const float* emb_b   = (const float*)d_in[7];
    const float* msg_w1  = (const float*)d_in[8];
    const float* msg_b1  = (const float*)d_in[9];
    const float* msg_g1  = (const float*)d_in[10];
    const float* msg_be1 = (const float*)d_in[11];
    const float* msg_w2  = (const float*)d_in[12];
    const float* msg_b2  = (const float*)d_in[13];
    const float* msg_g2  = (const float*)d_in[14];
    const float* msg_be2 = (const float*)d_in[15];
    const float* upd_w1  = (const float*)d_in[16];
    const float* upd_b1  = (const float*)d_in[17];
    const float* upd_g1  = (const float*)d_in[18];
    const float* upd_be1 = (const float*)d_in[19];
    const float* upd_w2  = (const float*)d_in[20];
    const float* upd_b2  = (const float*)d_in[21];
    const float* upd_g2  = (const float*)d_in[22];
    const float* upd_be2 = (const float*)d_in[23];
    const float* pred_w1 = (const float*)d_in[24];
    const float* pred_b1 = (const float*)d_in[25];
    const float* pred_w2 = (const float*)d_in[26];
    const float* pred_b2 = (const float*)d_in[27];

    char* ws = (char*)d_ws;
    float*          h      = (float*)          ws;                 // 25,600,000
    unsigned short* hb     = (unsigned short*)(ws + 25600000);     // 12,800,000
    float*          aggr   = (float*)         (ws + 38400000);     // 25,600,000
    float*          dist   = (float*)         (ws + 64000000);     //  3,200,000
    float*          pooled = (float*)         (ws + 67200000);     //     32,768
    unsigned short* packed = (unsigned short*)(ws + 67232768);     //    983,040
    int*            cnt    = (int*)           (ws + 68215808);     //    200,704
    int*            cur    = (int*)           (ws + 68416512);     //    200,704
    int*            sidx   = (int*)           (ws + 68617216);     //  3,200,000
    int*            ssrc   = (int*)           (ws + 71817216);     //  3,200,000
    int*            sdst   = (int*)           (ws + 75017216);     //  3,200,000

    hipMemsetAsync(aggr, 0, (size_t)NN * HD * sizeof(float), stream);
    hipMemsetAsync(pooled, 0, (size_t)NG * HD * sizeof(float), stream);
    hipMemsetAsync(cnt, 0, (size_t)NN * sizeof(int), stream);

    dim3 pgrid(128, DEPTH * 4);
    pack_weights<<<pgrid, 256, 0, stream>>>(msg_w1, msg_w2, upd_w1, upd_w2, packed);
    embed_kernel<<<(NN * HD) / 256, 256, 0, stream>>>(x, emb_w, emb_b, h, hb);

    hist_kernel<<<NE / 256, 256, 0, stream>>>(ei, cnt);
    scan_kernel<<<1, 1024, 0, stream>>>(cnt, cur);
    scatter_kernel<<<NE / 256, 256, 0, stream>>>(ei, cur, sidx, ssrc, sdst);
    dist_kernel<<<NE / 256, 256, 0, stream>>>(pos, sidx, ssrc, sdst, cell, U, dist);

    for (int layer = 0; layer < DEPTH; ++layer) {
        const unsigned short* pl = packed + layer * 98304;
        edge_kernel<<<NE / 128, 256, 0, stream>>>(
            hb, dist, ssrc, sdst, pl,
            msg_w1 + layer*257*HD + 256*HD,
            msg_b1 + layer*HD, msg_g1 + layer*HD, msg_be1 + layer*HD,
            msg_b2 + layer*HD, msg_g2 + layer*HD, msg_be2 + layer*HD,
            aggr);
        node_kernel<<<(NN + 127) / 128, 256, 0, stream>>>(
            hb, aggr, pl + 49152,
            upd_b1 + layer*HD, upd_g1 + layer*HD, upd_be1 + layer*HD,
            upd_b2 + layer*HD, upd_g2 + layer*HD, upd_be2 + layer*HD,
            h);
    }

    pool_kernel<<<(NN + 255) / 256, 128, 0, stream>>>(h, bids, pooled);
    pred_kernel<<<NG, 128, 0, stream>>>(pooled, pred_w1, pred_b1, pred_w2, pred_b2, (float*)d_out);
}

// Round 8
// 1414.478 us; speedup vs baseline: 1.3257x; 1.0527x over previous
//
#include <hip/hip_runtime.h>
#include <hip/hip_bf16.h>

#define NN 50000
#define NE 800000
#define HD 128
#define DEPTH 5
#define NG 64
#define LNEPS 1e-5f

typedef __attribute__((ext_vector_type(8))) short bf8;   // 8 x bf16
typedef __attribute__((ext_vector_type(4))) float f4;

// compiler-scheduled RNE conversions (m240: do NOT hand-write cvt_pk asm)
static __device__ __forceinline__ unsigned short bf1(float x) {
    __hip_bfloat16 b = __float2bfloat16(x);
    unsigned short r;
    __builtin_memcpy(&r, &b, 2);
    return r;
}
static __device__ __forceinline__ unsigned int cvt2(float a, float b) {
    float2 t; t.x = a; t.y = b;
    __hip_bfloat162 h = __float22bfloat162_rn(t);
    unsigned int r;
    __builtin_memcpy(&r, &h, 4);
    return r;
}

// ---------------------------------------------------------------------------
// Pack weights (K x 128 f32 row-major) into bf16 MFMA B-fragment layout:
// packed[s*4096 + f*512 + lane*8 + e] = W[krow][f*16 + (lane&15)],
// krow = s*32 + (lane>>4)*8 + e, except for the K=128 second-layer mats
// (which&1): krow = pinv(k) = (k&7)*16 + (k>>3) — matches the p-space t1
// layout (p(n) = (n&15)*8 + (n>>4)) used for the GEMM2 A-operand.
// ---------------------------------------------------------------------------
__global__ void pack_weights(const float* __restrict__ msg_w1, const float* __restrict__ msg_w2,
                             const float* __restrict__ upd_w1, const float* __restrict__ upd_w2,
                             unsigned short* __restrict__ packed) {
    const int which = blockIdx.y & 3, layer = blockIdx.y >> 2;
    const int t = blockIdx.x * 256 + threadIdx.x;
    const float* src; int K; unsigned short* dst;
    unsigned short* lbase = packed + layer * 98304;
    if (which == 0)      { src = msg_w1 + layer*257*HD; K = 256; dst = lbase; }
    else if (which == 1) { src = msg_w2 + layer*HD*HD;  K = 128; dst = lbase + 32768; }
    else if (which == 2) { src = upd_w1 + layer*256*HD; K = 256; dst = lbase + 49152; }
    else                 { src = upd_w2 + layer*HD*HD;  K = 128; dst = lbase + 81920; }
    if (t >= K * HD) return;
    const int e = t & 7, l = (t >> 3) & 63, f = (t >> 9) & 7, s = t >> 12;
    const int kk = s*32 + ((l >> 4) << 3) + e;
    const int k = (which & 1) ? ((kk & 7)*16 + (kk >> 3)) : kk;   // pinv for layer-2 mats
    const int n = f*16 + (l & 15);
    dst[t] = bf1(src[k*HD + n]);
}

__global__ void embed_kernel(const float* __restrict__ x, const float* __restrict__ emb_w,
                             const float* __restrict__ emb_b,
                             float* __restrict__ h, unsigned short* __restrict__ hb) {
    const int i = blockIdx.x * 256 + threadIdx.x;      // N*H exact
    const int n = i >> 7, j = i & 127;
    const float v = x[n] * emb_w[j] + emb_b[j];
    h[i] = v; hb[i] = bf1(v);
}

// --------------------- counting sort of edges by dst -----------------------
__global__ void hist_kernel(const int* __restrict__ ei, int* __restrict__ cnt) {
    const int e = blockIdx.x * 256 + threadIdx.x;      // NE exact
    atomicAdd(&cnt[ei[NE + e]], 1);
}

__global__ __launch_bounds__(1024) void scan_kernel(const int* __restrict__ cnt,
                                                    int* __restrict__ cur) {
    __shared__ int part[1024];
    const int t = threadIdx.x;
    const int per = 49;                                 // 1024*49 >= NN
    const int base = t * per;
    int s = 0;
    for (int i = 0; i < per; ++i) { const int idx = base + i; if (idx < NN) s += cnt[idx]; }
    part[t] = s; __syncthreads();
    for (int st = 1; st < 1024; st <<= 1) {
        const int v = (t >= st) ? part[t - st] : 0;
        __syncthreads();
        part[t] += v;
        __syncthreads();
    }
    int run = (t == 0) ? 0 : part[t - 1];
    for (int i = 0; i < per; ++i) {
        const int idx = base + i;
        if (idx < NN) { cur[idx] = run; run += cnt[idx]; }
    }
}

__global__ void scatter_kernel(const int* __restrict__ ei, int* __restrict__ cur,
                               int* __restrict__ sidx, int* __restrict__ ssrc,
                               int* __restrict__ sdst) {
    const int e = blockIdx.x * 256 + threadIdx.x;      // NE exact
    const int d = ei[NE + e];
    const int p = atomicAdd(&cur[d], 1);
    sidx[p] = e; ssrc[p] = ei[e]; sdst[p] = d;
}

// dist in SORTED edge order
__global__ void dist_kernel(const float* __restrict__ pos, const int* __restrict__ sidx,
                            const int* __restrict__ ssrc, const int* __restrict__ sdst,
                            const float* __restrict__ cell, const float* __restrict__ U,
                            float* __restrict__ dist) {
    const int p = blockIdx.x * 256 + threadIdx.x;      // NE exact
    const int e = sidx[p];
    const int s = ssrc[p], d = sdst[p];
    const float c0 = cell[e*3], c1 = cell[e*3+1], c2 = cell[e*3+2];
    const float ox = c0*U[0] + c1*U[3] + c2*U[6];
    const float oy = c0*U[1] + c1*U[4] + c2*U[7];
    const float oz = c0*U[2] + c1*U[5] + c2*U[8];
    const float dx = pos[d*3]   - ox - pos[s*3];
    const float dy = pos[d*3+1] - oy - pos[s*3+1];
    const float dz = pos[d*3+2] - oz - pos[s*3+2];
    dist[p] = sqrtf(dx*dx + dy*dy + dz*dz);
}

// ---------------------------------------------------------------------------
// Edge MLP, dst-sorted, 64 edges/block, 2 waves x 32 rows (M=32/wave keeps
// the R4 B-reuse). LDS 16.5KB -> ~9 blocks/CU for latency hiding.
// t1/msg in p-space: one ds_write_b128 per row-slice, cvt via intrinsics.
// ---------------------------------------------------------------------------
__global__ __launch_bounds__(128, 4) void edge_kernel(
    const unsigned short* __restrict__ hb, const float* __restrict__ dist,
    const int* __restrict__ ssrc, const int* __restrict__ sdst,
    const unsigned short* __restrict__ pw,
    const float* __restrict__ w1last, const float* __restrict__ b1,
    const float* __restrict__ g1, const float* __restrict__ be1,
    const float* __restrict__ b2, const float* __restrict__ g2,
    const float* __restrict__ be2, float* __restrict__ aggr)
{
    __shared__ unsigned short lds[64 * 128];           // 16KB: [row][p-feat]
    __shared__ int dstl[64];
    char* ldsb = (char*)lds;
    const int tid = threadIdx.x, blk = blockIdx.x;
    const int l = tid & 63, wv = tid >> 6;             // wv in {0,1}
    const int li = l & 15, gq = l >> 4;

    if (tid < 64) dstl[tid] = sdst[blk*64 + tid];

    const int rowA = wv*32 + li, rowB = rowA + 16;
    const int eA = blk*64 + rowA, eB = blk*64 + rowB;
    const unsigned short* pDA = hb + sdst[eA]*HD + gq*8;
    const unsigned short* pSA = hb + ssrc[eA]*HD + gq*8;
    const unsigned short* pDB = hb + sdst[eB]*HD + gq*8;
    const unsigned short* pSB = hb + ssrc[eB]*HD + gq*8;

    f4 acc[2][8];
    #pragma unroll
    for (int m = 0; m < 2; ++m)
        #pragma unroll
        for (int f = 0; f < 8; ++f) { f4 z = {0.f,0.f,0.f,0.f}; acc[m][f] = z; }

    #pragma unroll
    for (int s = 0; s < 8; ++s) {
        bf8 breg[8];
        #pragma unroll
        for (int f = 0; f < 8; ++f) breg[f] = *(const bf8*)(pw + s*4096 + f*512 + l*8);
        const bf8 aA = (s < 4) ? *(const bf8*)(pDA + s*32) : *(const bf8*)(pSA + (s-4)*32);
        const bf8 aB = (s < 4) ? *(const bf8*)(pDB + s*32) : *(const bf8*)(pSB + (s-4)*32);
        #pragma unroll
        for (int f = 0; f < 8; ++f) {
            acc[0][f] = __builtin_amdgcn_mfma_f32_16x16x32_bf16(aA, breg[f], acc[0][f], 0, 0, 0);
            acc[1][f] = __builtin_amdgcn_mfma_f32_16x16x32_bf16(aB, breg[f], acc[1][f], 0, 0, 0);
        }
    }

    // epilogue 1: acc += b1 + dist*w1last (in-place) -> LN -> relu -> b128 p-space write
    {
        float bb[8], wl[8], gg[8], be[8];
        #pragma unroll
        for (int f = 0; f < 8; ++f) {
            const int n = f*16 + li;
            bb[f] = b1[n]; wl[f] = w1last[n]; gg[f] = g1[n]; be[f] = be1[n];
        }
        #pragma unroll
        for (int m = 0; m < 2; ++m) {
            const float4 d4 = *(const float4*)(dist + blk*64 + wv*32 + m*16 + gq*4);
            const float dsv[4] = {d4.x, d4.y, d4.z, d4.w};
            float ps[4] = {0,0,0,0}, pq[4] = {0,0,0,0};
            #pragma unroll
            for (int f = 0; f < 8; ++f)
                #pragma unroll
                for (int r = 0; r < 4; ++r) {
                    const float v = acc[m][f][r] + bb[f] + dsv[r]*wl[f];
                    acc[m][f][r] = v;
                    ps[r] += v; pq[r] += v*v;
                }
            #pragma unroll
            for (int mm = 1; mm < 16; mm <<= 1)
                #pragma unroll
                for (int r = 0; r < 4; ++r) {
                    ps[r] += __shfl_xor(ps[r], mm);
                    pq[r] += __shfl_xor(pq[r], mm);
                }
            #pragma unroll
            for (int r = 0; r < 4; ++r) {
                const float mean = ps[r] * (1.f/HD);
                const float rstd = rsqrtf(pq[r]*(1.f/HD) - mean*mean + LNEPS);
                const int row = wv*32 + m*16 + gq*4 + r;
                float vv[8];
                #pragma unroll
                for (int f = 0; f < 8; ++f)
                    vv[f] = fmaxf((acc[m][f][r] - mean)*rstd*gg[f] + be[f], 0.f);
                uint4 u;
                u.x = cvt2(vv[0], vv[1]); u.y = cvt2(vv[2], vv[3]);
                u.z = cvt2(vv[4], vv[5]); u.w = cvt2(vv[6], vv[7]);
                *(uint4*)(ldsb + ((row*256 + li*16) ^ ((row & 7) << 4))) = u;
            }
        }
    }
    // rows are wave-private: no barrier before GEMM2

    const unsigned short* pw2 = pw + 32768;
    f4 acc2[2][8];
    #pragma unroll
    for (int m = 0; m < 2; ++m)
        #pragma unroll
        for (int f = 0; f < 8; ++f) { f4 z = {0.f,0.f,0.f,0.f}; acc2[m][f] = z; }
    #pragma unroll
    for (int s = 0; s < 4; ++s) {
        bf8 breg[8];
        #pragma unroll
        for (int f = 0; f < 8; ++f) breg[f] = *(const bf8*)(pw2 + s*4096 + f*512 + l*8);
        #pragma unroll
        for (int m = 0; m < 2; ++m) {
            const int ar = wv*32 + m*16 + li;
            const bf8 a = *(const bf8*)(ldsb + ((ar*256 + s*64 + gq*16) ^ ((ar & 7) << 4)));
            #pragma unroll
            for (int f = 0; f < 8; ++f)
                acc2[m][f] = __builtin_amdgcn_mfma_f32_16x16x32_bf16(a, breg[f], acc2[m][f], 0, 0, 0);
        }
    }

    // epilogue 2: +b2 (in-place) -> LN -> relu -> b128 p-space msg write
    {
        float bb2[8], gg2[8], be2v[8];
        #pragma unroll
        for (int f = 0; f < 8; ++f) {
            const int n = f*16 + li;
            bb2[f] = b2[n]; gg2[f] = g2[n]; be2v[f] = be2[n];
        }
        #pragma unroll
        for (int m = 0; m < 2; ++m) {
            float ps[4] = {0,0,0,0}, pq[4] = {0,0,0,0};
            #pragma unroll
            for (int f = 0; f < 8; ++f)
                #pragma unroll
                for (int r = 0; r < 4; ++r) {
                    const float v = acc2[m][f][r] + bb2[f];
                    acc2[m][f][r] = v;
                    ps[r] += v; pq[r] += v*v;
                }
            #pragma unroll
            for (int mm = 1; mm < 16; mm <<= 1)
                #pragma unroll
                for (int r = 0; r < 4; ++r) {
                    ps[r] += __shfl_xor(ps[r], mm);
                    pq[r] += __shfl_xor(pq[r], mm);
                }
            #pragma unroll
            for (int r = 0; r < 4; ++r) {
                const float mean = ps[r] * (1.f/HD);
                const float rstd = rsqrtf(pq[r]*(1.f/HD) - mean*mean + LNEPS);
                const int row = wv*32 + m*16 + gq*4 + r;
                float vv[8];
                #pragma unroll
                for (int f = 0; f < 8; ++f)
                    vv[f] = fmaxf((acc2[m][f][r] - mean)*rstd*gg2[f] + be2v[f], 0.f);
                uint4 u;
                u.x = cvt2(vv[0], vv[1]); u.y = cvt2(vv[2], vv[3]);
                u.z = cvt2(vv[4], vv[5]); u.w = cvt2(vv[6], vv[7]);
                *(uint4*)(ldsb + ((row*256 + li*16) ^ ((row & 7) << 4))) = u;
            }
        }
    }
    __syncthreads();

    // segmented reduce over 64 sorted rows: one thread per p-col
    {
        const int j = tid;                              // 0..127
        const int jj = (j & 7)*16 + (j >> 3);          // original feature
        int curd = dstl[0];
        float a0 = 0.f;
        #pragma unroll 4
        for (int row = 0; row < 64; ++row) {
            const int d = dstl[row];
            const unsigned short u = *(const unsigned short*)(ldsb + ((row*256 + j*2) ^ ((row & 7) << 4)));
            const float v = __uint_as_float(((unsigned int)u) << 16);
            if (d != curd) { unsafeAtomicAdd(&aggr[curd*HD + jj], a0); a0 = 0.f; curd = d; }
            a0 += v;
        }
        unsafeAtomicAdd(&aggr[curd*HD + jj], a0);
    }
}

// ---------------------------------------------------------------------------
// Node update, 64 nodes/block, 2 waves x 32 rows. Zeroes aggr in-place.
// ---------------------------------------------------------------------------
__global__ __launch_bounds__(128, 4) void node_kernel(
    unsigned short* __restrict__ hb, float* __restrict__ aggr,
    const unsigned short* __restrict__ pw,
    const float* __restrict__ b1, const float* __restrict__ g1, const float* __restrict__ be1,
    const float* __restrict__ b2, const float* __restrict__ g2, const float* __restrict__ be2,
    float* __restrict__ h)
{
    __shared__ unsigned short lds[64 * 128];
    char* ldsb = (char*)lds;
    const int tid = threadIdx.x, blk = blockIdx.x;
    const int l = tid & 63, wv = tid >> 6;
    const int li = l & 15, gq = l >> 4;

    const int rowA = wv*32 + li, rowB = rowA + 16;
    const int nA = blk*64 + rowA, nB = blk*64 + rowB;
    const int ncA = (nA < NN) ? nA : NN - 1;
    const int ncB = (nB < NN) ? nB : NN - 1;
    const unsigned short* pHA = hb + ncA*HD + gq*8;
    const unsigned short* pHB = hb + ncB*HD + gq*8;
    float* pAA = aggr + ncA*HD + gq*8;
    float* pAB = aggr + ncB*HD + gq*8;

    f4 acc[2][8];
    #pragma unroll
    for (int m = 0; m < 2; ++m)
        #pragma unroll
        for (int f = 0; f < 8; ++f) { f4 z = {0.f,0.f,0.f,0.f}; acc[m][f] = z; }

    #pragma unroll
    for (int s = 0; s < 8; ++s) {
        bf8 breg[8];
        #pragma unroll
        for (int f = 0; f < 8; ++f) breg[f] = *(const bf8*)(pw + s*4096 + f*512 + l*8);
        bf8 aA, aB;
        if (s < 4) {
            aA = *(const bf8*)(pHA + s*32);
            aB = *(const bf8*)(pHB + s*32);
        } else {
            const float4 a0 = *(const float4*)(pAA + (s-4)*32);
            const float4 a1 = *(const float4*)(pAA + (s-4)*32 + 4);
            const float4 c0 = *(const float4*)(pAB + (s-4)*32);
            const float4 c1 = *(const float4*)(pAB + (s-4)*32 + 4);
            union { unsigned int u[4]; bf8 v; } pk;
            pk.u[0] = cvt2(a0.x, a0.y); pk.u[1] = cvt2(a0.z, a0.w);
            pk.u[2] = cvt2(a1.x, a1.y); pk.u[3] = cvt2(a1.z, a1.w);
            aA = pk.v;
            pk.u[0] = cvt2(c0.x, c0.y); pk.u[1] = cvt2(c0.z, c0.w);
            pk.u[2] = cvt2(c1.x, c1.y); pk.u[3] = cvt2(c1.z, c1.w);
            aB = pk.v;
        }
        #pragma unroll
        for (int f = 0; f < 8; ++f) {
            acc[0][f] = __builtin_amdgcn_mfma_f32_16x16x32_bf16(aA, breg[f], acc[0][f], 0, 0, 0);
            acc[1][f] = __builtin_amdgcn_mfma_f32_16x16x32_bf16(aB, breg[f], acc[1][f], 0, 0, 0);
        }
    }

    // zero aggr slices for next layer (loads consumed above)
    {
        const float4 z = {0.f,0.f,0.f,0.f};
        #pragma unroll
        for (int s = 0; s < 4; ++s) {
            if (nA < NN) { *(float4*)(pAA + s*32) = z; *(float4*)(pAA + s*32 + 4) = z; }
            if (nB < NN) { *(float4*)(pAB + s*32) = z; *(float4*)(pAB + s*32 + 4) = z; }
        }
    }

    // epilogue 1 -> p-space t1
    {
        float bb[8], gg[8], be[8];
        #pragma unroll
        for (int f = 0; f < 8; ++f) {
            const int n = f*16 + li;
            bb[f] = b1[n]; gg[f] = g1[n]; be[f] = be1[n];
        }
        #pragma unroll
        for (int m = 0; m < 2; ++m) {
            float ps[4] = {0,0,0,0}, pq[4] = {0,0,0,0};
            #pragma unroll
            for (int f = 0; f < 8; ++f)
                #pragma unroll
                for (int r = 0; r < 4; ++r) {
                    const float v = acc[m][f][r] + bb[f];
                    acc[m][f][r] = v;
                    ps[r] += v; pq[r] += v*v;
                }
            #pragma unroll
            for (int mm = 1; mm < 16; mm <<= 1)
                #pragma unroll
                for (int r = 0; r < 4; ++r) {
                    ps[r] += __shfl_xor(ps[r], mm);
                    pq[r] += __shfl_xor(pq[r], mm);
                }
            #pragma unroll
            for (int r = 0; r < 4; ++r) {
                const float mean = ps[r] * (1.f/HD);
                const float rstd = rsqrtf(pq[r]*(1.f/HD) - mean*mean + LNEPS);
                const int row = wv*32 + m*16 + gq*4 + r;
                float vv[8];
                #pragma unroll
                for (int f = 0; f < 8; ++f)
                    vv[f] = fmaxf((acc[m][f][r] - mean)*rstd*gg[f] + be[f], 0.f);
                uint4 u;
                u.x = cvt2(vv[0], vv[1]); u.y = cvt2(vv[2], vv[3]);
                u.z = cvt2(vv[4], vv[5]); u.w = cvt2(vv[6], vv[7]);
                *(uint4*)(ldsb + ((row*256 + li*16) ^ ((row & 7) << 4))) = u;
            }
        }
    }

    const unsigned short* pw2 = pw + 32768;
    f4 acc2[2][8];
    #pragma unroll
    for (int m = 0; m < 2; ++m)
        #pragma unroll
        for (int f = 0; f < 8; ++f) { f4 z = {0.f,0.f,0.f,0.f}; acc2[m][f] = z; }
    #pragma unroll
    for (int s = 0; s < 4; ++s) {
        bf8 breg[8];
        #pragma unroll
        for (int f = 0; f < 8; ++f) breg[f] = *(const bf8*)(pw2 + s*4096 + f*512 + l*8);
        #pragma unroll
        for (int m = 0; m < 2; ++m) {
            const int ar = wv*32 + m*16 + li;
            const bf8 a = *(const bf8*)(ldsb + ((ar*256 + s*64 + gq*16) ^ ((ar & 7) << 4)));
            #pragma unroll
            for (int f = 0; f < 8; ++f)
                acc2[m][f] = __builtin_amdgcn_mfma_f32_16x16x32_bf16(a, breg[f], acc2[m][f], 0, 0, 0);
        }
    }

    // epilogue 2: LN -> relu -> residual h += u, refresh hb
    {
        float bb2[8], gg2[8], be2v[8];
        #pragma unroll
        for (int f = 0; f < 8; ++f) {
            const int n = f*16 + li;
            bb2[f] = b2[n]; gg2[f] = g2[n]; be2v[f] = be2[n];
        }
        #pragma unroll
        for (int m = 0; m < 2; ++m) {
            float ps[4] = {0,0,0,0}, pq[4] = {0,0,0,0};
            #pragma unroll
            for (int f = 0; f < 8; ++f)
                #pragma unroll
                for (int r = 0; r < 4; ++r) {
                    const float v = acc2[m][f][r] + bb2[f];
                    acc2[m][f][r] = v;
                    ps[r] += v; pq[r] += v*v;
                }
            #pragma unroll
            for (int mm = 1; mm < 16; mm <<= 1)
                #pragma unroll
                for (int r = 0; r < 4; ++r) {
                    ps[r] += __shfl_xor(ps[r], mm);
                    pq[r] += __shfl_xor(pq[r], mm);
                }
            #pragma unroll
            for (int r = 0; r < 4; ++r) {
                const int node = blk*64 + wv*32 + m*16 + gq*4 + r;
                if (node < NN) {
                    const float mean = ps[r] * (1.f/HD);
                    const float rstd = rsqrtf(pq[r]*(1.f/HD) - mean*mean + LNEPS);
                    #pragma unroll
                    for (int f = 0; f < 8; ++f) {
                        const int n = f*16 + li;
                        float v = (acc2[m][f][r] - mean)*rstd*gg2[f] + be2v[f];
                        v = fmaxf(v, 0.f);
                        const int idx = node*HD + n;
                        const float nh = h[idx] + v;
                        h[idx] = nh;
                        hb[idx] = bf1(nh);
                    }
                }
            }
        }
    }
}

// global_add_pool over sorted batch_ids
__global__ void pool_kernel(const float* __restrict__ h, const int* __restrict__ bids,
                            float* __restrict__ pooled) {
    const int j = threadIdx.x;                  // 128 features
    const int n0 = blockIdx.x * 256;
    if (n0 >= NN) return;
    int cur = bids[n0];
    float acc = 0.f;
    for (int i = 0; i < 256; ++i) {
        const int n = n0 + i;
        if (n >= NN) break;
        const int b = bids[n];
        if (b != cur) { unsafeAtomicAdd(&pooled[cur*HD + j], acc); acc = 0.f; cur = b; }
        acc += h[n*HD + j];
    }
    unsafeAtomicAdd(&pooled[cur*HD + j], acc);
}

__global__ void pred_kernel(const float* __restrict__ pooled, const float* __restrict__ w1,
                            const float* __restrict__ pb1, const float* __restrict__ w2,
                            const float* __restrict__ pb2, float* __restrict__ out) {
    const int g = blockIdx.x, j = threadIdx.x;  // 128 threads
    __shared__ float pg[128];
    __shared__ float red[128];
    pg[j] = pooled[g*HD + j];
    __syncthreads();
    float z = pb1[j];
    for (int k = 0; k < 128; ++k) z += pg[k] * w1[k*HD + j];
    red[j] = fmaxf(z, 0.f) * w2[j];
    __syncthreads();
    for (int st = 64; st > 0; st >>= 1) {
        if (j < st) red[j] += red[j + st];
        __syncthreads();
    }
    if (j == 0) out[g] = red[0] + pb2[0];
}

extern "C" void kernel_launch(void* const* d_in, const int* in_sizes, int n_in,
                              void* d_out, int out_size, void* d_ws, size_t ws_size,
                              hipStream_t stream) {
    const float* x       = (const float*)d_in[0];
    const float* pos     = (const float*)d_in[1];
    const int*   ei      = (const int*)  d_in[2];
    const float* cell    = (const float*)d_in[3];
    const float* U       = (const float*)d_in[4];
    const int*   bids    = (const int*)  d_in[5];
    const float* emb_w   = (const float*)d_in[6];
    const float* emb_b   = (const float*)d_in[7];
    const float* msg_w1  = (const float*)d_in[8];
    const float* msg_b1  = (const float*)d_in[9];
    const float* msg_g1  = (const float*)d_in[10];
    const float* msg_be1 = (const float*)d_in[11];
    const float* msg_w2  = (const float*)d_in[12];
    const float* msg_b2  = (const float*)d_in[13];
    const float* msg_g2  = (const float*)d_in[14];
    const float* msg_be2 = (const float*)d_in[15];
    const float* upd_w1  = (const float*)d_in[16];
    const float* upd_b1  = (const float*)d_in[17];
    const float* upd_g1  = (const float*)d_in[18];
    const float* upd_be1 = (const float*)d_in[19];
    const float* upd_w2  = (const float*)d_in[20];
    const float* upd_b2  = (const float*)d_in[21];
    const float* upd_g2  = (const float*)d_in[22];
    const float* upd_be2 = (const float*)d_in[23];
    const float* pred_w1 = (const float*)d_in[24];
    const float* pred_b1 = (const float*)d_in[25];
    const float* pred_w2 = (const float*)d_in[26];
    const float* pred_b2 = (const float*)d_in[27];

    char* ws = (char*)d_ws;
    float*          h      = (float*)          ws;                 // 25,600,000
    unsigned short* hb     = (unsigned short*)(ws + 25600000);     // 12,800,000
    float*          aggr   = (float*)         (ws + 38400000);     // 25,600,000
    float*          dist   = (float*)         (ws + 64000000);     //  3,200,000
    float*          pooled = (float*)         (ws + 67200000);     //     32,768
    unsigned short* packed = (unsigned short*)(ws + 67232768);     //    983,040
    int*            cnt    = (int*)           (ws + 68215808);     //    200,704
    int*            cur    = (int*)           (ws + 68416512);     //    200,704
    int*            sidx   = (int*)           (ws + 68617216);     //  3,200,000
    int*            ssrc   = (int*)           (ws + 71817216);     //  3,200,000
    int*            sdst   = (int*)           (ws + 75017216);     //  3,200,000

    hipMemsetAsync(aggr, 0, (size_t)NN * HD * sizeof(float), stream);
    hipMemsetAsync(pooled, 0, (size_t)NG * HD * sizeof(float), stream);
    hipMemsetAsync(cnt, 0, (size_t)NN * sizeof(int), stream);

    dim3 pgrid(128, DEPTH * 4);
    pack_weights<<<pgrid, 256, 0, stream>>>(msg_w1, msg_w2, upd_w1, upd_w2, packed);
    embed_kernel<<<(NN * HD) / 256, 256, 0, stream>>>(x, emb_w, emb_b, h, hb);

    hist_kernel<<<NE / 256, 256, 0, stream>>>(ei, cnt);
    scan_kernel<<<1, 1024, 0, stream>>>(cnt, cur);
    scatter_kernel<<<NE / 256, 256, 0, stream>>>(ei, cur, sidx, ssrc, sdst);
    dist_kernel<<<NE / 256, 256, 0, stream>>>(pos, sidx, ssrc, sdst, cell, U, dist);

    for (int layer = 0; layer < DEPTH; ++layer) {
        const unsigned short* pl = packed + layer * 98304;
        edge_kernel<<<NE / 64, 128, 0, stream>>>(
            hb, dist, ssrc, sdst, pl,
            msg_w1 + layer*257*HD + 256*HD,
            msg_b1 + layer*HD, msg_g1 + layer*HD, msg_be1 + layer*HD,
            msg_b2 + layer*HD, msg_g2 + layer*HD, msg_be2 + layer*HD,
            aggr);
        node_kernel<<<(NN + 63) / 64, 128, 0, stream>>>(
            hb, aggr, pl + 49152,
            upd_b1 + layer*HD, upd_g1 + layer*HD, upd_be1 + layer*HD,
            upd_b2 + layer*HD, upd_g2 + layer*HD, upd_be2 + layer*HD,
            h);
    }

    pool_kernel<<<(NN + 255) / 256, 128, 0, stream>>>(h, bids, pooled);
    pred_kernel<<<NG, 128, 0, stream>>>(pooled, pred_w1, pred_b1, pred_w2, pred_b2, (float*)d_out);
}